// Round 7
// baseline (241.341 us; speedup 1.0000x reference)
//
#include <hip/hip_runtime.h>
#include <hip/hip_cooperative_groups.h>

namespace cg = cooperative_groups;

// ColorHistogramLoss: soft histogram (Gaussian kernel, 64 bins) over
// pred/target (4,3,256,256) fp32, normalized, cumsum, mean |cdf diff|.
//
// v7: single cooperative kernel (hist + final fused via grid.sync()).
//   v6 post-mortem: LDS-op slope is ~0.075us/op (<< issue-bound 0.24) ->
//   main loop no longer dominant; residual over the 41us harness fill is
//   largely the 2nd dispatch + single-CU final. Fusion removes the
//   final launch+gap and distributes its reads over 12 CUs.
//   Phase 1 numerics identical to v6 (row-major lane-private LDS,
//   bank = lane%32 data-independent conflict-free, R=4 / 9-tap window,
//   batched read->fma->write RMW).
//
// Structure (one dispatch):
//   fused_kernel: 768 blocks x 128 thr (3 blocks/CU, co-resident);
//     ph1: per-block 64-bin partial -> d_ws
//     grid.sync()
//     ph2: blocks 0..11: per-channel cdf |diff| sum -> d_ws scratch
//     grid.sync()
//     ph3: block 0: wave-reduce 12 scalars -> out[0]

#define BINS 64
#define NCH 12            // B*C = 4*3
#define HW 65536          // 256*256
#define BPC 32            // pixel-chunks (blocks) per channel-image
#define PIX_PER_BLOCK (HW / BPC)              // 2048
#define THREADS 128
#define PPT (PIX_PER_BLOCK / THREADS)         // 16 pixels per thread
#define R 4               // Gaussian support radius (edge weight e^-8)
#define WIN (2 * R + 1)   // 9 taps
#define PADBINS (BINS + 2 * R)   // 72 rows: row = bin + R
#define NW (THREADS / 64) // 2 waves
#define NBLK (2 * NCH * BPC)     // 768 blocks, all co-resident

__device__ __forceinline__ float fast_exp2(float x) {
#if __has_builtin(__builtin_amdgcn_exp2f)
    return __builtin_amdgcn_exp2f(x);   // v_exp_f32
#else
    return exp2f(x);
#endif
}

// weight for bin i-R+t (t=0..8): exp(-(f-(t-R))^2/2) = CK[t] * P_t,
//   P_0 = exp(-f^2/2 - R*f)  (one exp2)    B = exp(f)  (one exp2)
//   P_{t+1} = P_t * B ;  CK[t] = exp(-(t-R)^2/2)  (compile-time)
__global__ __launch_bounds__(THREADS) void fused_kernel(
        const float* __restrict__ pred,
        const float* __restrict__ target,
        float* __restrict__ part_out,
        float* __restrict__ out) {
    constexpr float CK[WIN] = {
        3.3546262790251185e-04f, 1.1108996538242306e-02f,
        1.3533528323661270e-01f, 6.0653065971263342e-01f, 1.0f,
        6.0653065971263342e-01f, 1.3533528323661270e-01f,
        1.1108996538242306e-02f, 3.3546262790251185e-04f };

    // ---------------- phase 1: per-block histogram partial ----------------
    {
        const int blk   = blockIdx.x;
        const int ch    = blk / BPC;        // 0..23 (0..11 pred, 12..23 target)
        const int chunk = blk % BPC;
        const float* src = (ch < NCH) ? (pred + (size_t)ch * HW)
                                      : (target + (size_t)(ch - NCH) * HW);

        // row-major lane-private columns: bank = lane%32 for every tap row,
        // conflict-free (2-way) independent of pixel data. No atomics.
        __shared__ float h[NW][PADBINS][64];   // 36864 B
        __shared__ float part[NW][BINS];

        const int wv   = threadIdx.x >> 6;
        const int lane = threadIdx.x & 63;

        // zero h: 9216 dwords = 2304 float4 / 128 thr = 18 each (exact)
        {
            float4* hz = (float4*)&h[0][0][0];
            #pragma unroll
            for (int t = 0; t < NW * PADBINS * 64 / 4 / THREADS; ++t)
                hz[threadIdx.x + t * THREADS] = make_float4(0.f, 0.f, 0.f, 0.f);
        }
        __syncthreads();

        // 512 float4 per block; thread t loads f4[t + k*128] (coalesced).
        const float4* src4 = (const float4*)(src + chunk * PIX_PER_BLOCK);
        float4 a = src4[threadIdx.x];
        float4 b = src4[threadIdx.x + THREADS];
        float4 c = src4[threadIdx.x + 2 * THREADS];
        float4 d = src4[threadIdx.x + 3 * THREADS];
        float px[PPT] = {a.x, a.y, a.z, a.w, b.x, b.y, b.z, b.w,
                         c.x, c.y, c.z, c.w, d.x, d.y, d.z, d.w};

        const float L  = 1.4426950408889634f;    // log2(e)
        const float L2 = 0.7213475204444817f;    // log2(e)/2

        #pragma unroll
        for (int p = 0; p < PPT; ++p) {
            float xt = px[p] * 64.0f - 0.5f;       // bin-center units
            float fi = rintf(xt);
            fi = fminf(fmaxf(fi, 0.0f), 63.0f);    // defensive clamp
            float f  = xt - fi;                    // [-0.5, 0.5]
            int   i  = (int)fi;                    // nearest bin -> rows i..i+8
            float P  = fast_exp2(-L2 * f * f - (float)R * L * f);
            float B  = fast_exp2(L * f);

            // batched RMW: 9 reads (one vaddr, offset:t*256) -> fma -> writes
            float v[WIN];
            #pragma unroll
            for (int t = 0; t < WIN; ++t) v[t] = h[wv][i + t][lane];
            #pragma unroll
            for (int t = 0; t < WIN; ++t) { v[t] = fmaf(P, CK[t], v[t]); P *= B; }
            #pragma unroll
            for (int t = 0; t < WIN; ++t) h[wv][i + t][lane] = v[t];
        }

        __syncthreads();

        // Per-wave column reduce: lane j sums 64 lane-columns at row j+R.
        // bank = (j+cc)%32: 2-way alias, free.
        {
            const int j = lane;
            float s = 0.0f;
            #pragma unroll
            for (int cc = 0; cc < 64; ++cc)
                s += h[wv][R + j][(j + cc) & 63];
            part[wv][j] = s;
        }
        __syncthreads();
        if (threadIdx.x < BINS) {
            const int j = threadIdx.x;
            part_out[blk * BINS + j] = part[0][j] + part[1][j];  // plain store
        }
    }

    cg::this_grid().sync();   // partials visible device-wide

    // ------ phase 2: blocks 0..11 -> per-channel sum |cdf_p - cdf_t| ------
    float* dvbuf = part_out + NBLK * BINS;   // 12-float scratch after partials
    if (blockIdx.x < NCH && threadIdx.x < 64) {
        const int w    = blockIdx.x;
        const int lane = threadIdx.x;

        float ph = 0.0f, th = 0.0f;
        #pragma unroll
        for (int c = 0; c < BPC; ++c) {
            ph += part_out[(w * BPC + c) * BINS + lane];
            th += part_out[((NCH + w) * BPC + c) * BINS + lane];
        }

        // inclusive scan over bins (wave64 shfl_up)
        float ps = ph, ts = th;
        #pragma unroll
        for (int d = 1; d < 64; d <<= 1) {
            float sa = __shfl_up(ps, d, 64);
            float sb = __shfl_up(ts, d, 64);
            if (lane >= d) { ps += sa; ts += sb; }
        }
        float ptot = __shfl(ps, 63, 64);
        float ttot = __shfl(ts, 63, 64);
        float pc = ps / (ptot + 1e-8f);
        float tc = ts / (ttot + 1e-8f);
        float dv = fabsf(pc - tc);

        #pragma unroll
        for (int k = 32; k >= 1; k >>= 1) dv += __shfl_xor(dv, k, 64);
        if (lane == 0) dvbuf[w] = dv;
    }

    cg::this_grid().sync();   // dv scalars visible

    // ---------------- phase 3: block 0 -> final mean scalar ----------------
    if (blockIdx.x == 0 && threadIdx.x < 64) {
        const int lane = threadIdx.x;
        float v = (lane < NCH) ? dvbuf[lane] : 0.0f;
        #pragma unroll
        for (int k = 32; k >= 1; k >>= 1) v += __shfl_xor(v, k, 64);
        if (lane == 0) out[0] = v / (float)(NCH * BINS);
    }
}

extern "C" void kernel_launch(void* const* d_in, const int* in_sizes, int n_in,
                              void* d_out, int out_size, void* d_ws, size_t ws_size,
                              hipStream_t stream) {
    const float* pred   = (const float*)d_in[0];
    const float* target = (const float*)d_in[1];
    float* part = (float*)d_ws;          // 768*64 partials + 12 dv scratch
    float* out  = (float*)d_out;

    void* args[] = { (void*)&pred, (void*)&target, (void*)&part, (void*)&out };
    hipLaunchCooperativeKernel((const void*)fused_kernel,
                               dim3(NBLK), dim3(THREADS), args, 0, stream);
}

// Round 8
// 68.445 us; speedup vs baseline: 3.5261x; 3.5261x over previous
//
#include <hip/hip_runtime.h>

// ColorHistogramLoss: soft histogram (Gaussian kernel, 64 bins) over
// pred/target (4,3,256,256) fp32, normalized, cumsum, mean |cdf diff|.
//
// v8: v6 structure (two dispatches — v7 post-mortem: grid.sync costs
//   ~160us on 8 XCDs, cooperative fusion dead) with occupancy raised
//   from 3 to 4 blocks/CU: BPC 32->64, PPT 16->8, grid 768->1536.
//   v7 counters showed OccupancyPercent ~17% (1.5 waves/SIMD) — the
//   per-pixel LDS read->fma->write round-trip (~120cy) was latency-
//   bound, explaining v6's shallow slope vs LDS op count. 4 blocks/CU
//   (149.5KB/160KB LDS) = 2 waves/SIMD.
//   Numerics unchanged: row-major lane-private LDS (bank = lane%32,
//   data-independent conflict-free), R=4 / 9-tap window, ratio
//   recurrence (2 exp2/px), batched read->fma->write RMW.
//
// Structure:
//   hist_kernel : 1536 blocks x 128 thr (4 blocks/CU); h[2][72][64],
//                 staggered column reduce, partial store to d_ws
//   final_kernel: 1 block x 768 thr (12 waves); sum 64 chunk partials
//                 (coalesced), wave scan -> cdf -> |diff| -> mean

#define BINS 64
#define NCH 12            // B*C = 4*3
#define HW 65536          // 256*256
#define BPC 64            // pixel-chunks (blocks) per channel-image
#define PIX_PER_BLOCK (HW / BPC)              // 1024
#define THREADS 128
#define PPT (PIX_PER_BLOCK / THREADS)         // 8 pixels per thread
#define R 4               // Gaussian support radius (edge weight e^-8)
#define WIN (2 * R + 1)   // 9 taps
#define PADBINS (BINS + 2 * R)   // 72 rows: row = bin + R
#define NW (THREADS / 64) // 2 waves
#define NBLK (2 * NCH * BPC)     // 1536 blocks

__device__ __forceinline__ float fast_exp2(float x) {
#if __has_builtin(__builtin_amdgcn_exp2f)
    return __builtin_amdgcn_exp2f(x);   // v_exp_f32
#else
    return exp2f(x);
#endif
}

// weight for bin i-R+t (t=0..8): exp(-(f-(t-R))^2/2) = CK[t] * P_t,
//   P_0 = exp(-f^2/2 - R*f)  (one exp2)    B = exp(f)  (one exp2)
//   P_{t+1} = P_t * B ;  CK[t] = exp(-(t-R)^2/2)  (compile-time)
__global__ __launch_bounds__(THREADS) void hist_kernel(
        const float* __restrict__ pred,
        const float* __restrict__ target,
        float* __restrict__ part_out) {
    constexpr float CK[WIN] = {
        3.3546262790251185e-04f, 1.1108996538242306e-02f,
        1.3533528323661270e-01f, 6.0653065971263342e-01f, 1.0f,
        6.0653065971263342e-01f, 1.3533528323661270e-01f,
        1.1108996538242306e-02f, 3.3546262790251185e-04f };

    const int blk   = blockIdx.x;
    const int ch    = blk / BPC;        // 0..23 (0..11 pred, 12..23 target)
    const int chunk = blk % BPC;
    const float* src = (ch < NCH) ? (pred + (size_t)ch * HW)
                                  : (target + (size_t)(ch - NCH) * HW);

    // Issue global loads FIRST so HBM latency hides under the LDS zero.
    const float4* src4 = (const float4*)(src + chunk * PIX_PER_BLOCK);
    float4 a = src4[threadIdx.x];
    float4 b = src4[threadIdx.x + THREADS];

    // row-major lane-private columns: bank = lane%32 for every tap row,
    // conflict-free (2-way) independent of pixel data. No atomics.
    __shared__ float h[NW][PADBINS][64];   // 36864 B
    __shared__ float part[NW][BINS];

    const int wv   = threadIdx.x >> 6;
    const int lane = threadIdx.x & 63;

    // zero h: 9216 dwords = 2304 float4 / 128 thr = 18 each (exact)
    {
        float4* hz = (float4*)&h[0][0][0];
        #pragma unroll
        for (int t = 0; t < NW * PADBINS * 64 / 4 / THREADS; ++t)
            hz[threadIdx.x + t * THREADS] = make_float4(0.f, 0.f, 0.f, 0.f);
    }
    __syncthreads();

    float px[PPT] = {a.x, a.y, a.z, a.w, b.x, b.y, b.z, b.w};

    const float L  = 1.4426950408889634f;    // log2(e)
    const float L2 = 0.7213475204444817f;    // log2(e)/2

    #pragma unroll
    for (int p = 0; p < PPT; ++p) {
        float xt = px[p] * 64.0f - 0.5f;       // bin-center units
        float fi = rintf(xt);
        fi = fminf(fmaxf(fi, 0.0f), 63.0f);    // defensive clamp
        float f  = xt - fi;                    // [-0.5, 0.5]
        int   i  = (int)fi;                    // nearest bin -> rows i..i+8
        float P  = fast_exp2(-L2 * f * f - (float)R * L * f);
        float B  = fast_exp2(L * f);

        // batched RMW: 9 reads (one vaddr, offset:t*256) -> 9 fma -> 9 writes
        float v[WIN];
        #pragma unroll
        for (int t = 0; t < WIN; ++t) v[t] = h[wv][i + t][lane];
        #pragma unroll
        for (int t = 0; t < WIN; ++t) { v[t] = fmaf(P, CK[t], v[t]); P *= B; }
        #pragma unroll
        for (int t = 0; t < WIN; ++t) h[wv][i + t][lane] = v[t];
    }

    __syncthreads();

    // Per-wave column reduce: lane j sums 64 lane-columns at row j+R.
    // bank = ((j+R)*64 + j+cc) % 32 = (j+cc)%32: 2-way alias, free.
    {
        const int j = lane;
        float s = 0.0f;
        #pragma unroll
        for (int cc = 0; cc < 64; ++cc)
            s += h[wv][R + j][(j + cc) & 63];
        part[wv][j] = s;
    }
    __syncthreads();
    if (threadIdx.x < BINS) {
        const int j = threadIdx.x;
        part_out[blk * BINS + j] = part[0][j] + part[1][j];  // plain store
    }
}

__global__ __launch_bounds__(NCH * 64) void final_kernel(
        const float* __restrict__ part, float* __restrict__ out) {
    const int w    = threadIdx.x >> 6;   // 0..11 -> (b,c) channel
    const int lane = threadIdx.x & 63;   // bin

    // sum the 64 chunk-partials for pred and target (coalesced per c,
    // independent loads -> pipelined).
    float ph = 0.0f, th = 0.0f;
    #pragma unroll 8
    for (int c = 0; c < BPC; ++c) {
        ph += part[(w * BPC + c) * BINS + lane];
        th += part[((NCH + w) * BPC + c) * BINS + lane];
    }

    // inclusive scan over bins (wave64 shfl_up)
    float ps = ph, ts = th;
    #pragma unroll
    for (int d = 1; d < 64; d <<= 1) {
        float a = __shfl_up(ps, d, 64);
        float b = __shfl_up(ts, d, 64);
        if (lane >= d) { ps += a; ts += b; }
    }
    float ptot = __shfl(ps, 63, 64);
    float ttot = __shfl(ts, 63, 64);
    float pc = ps / (ptot + 1e-8f);
    float tc = ts / (ttot + 1e-8f);
    float dv = fabsf(pc - tc);

    // wave reduce
    #pragma unroll
    for (int k = 32; k >= 1; k >>= 1) dv += __shfl_xor(dv, k, 64);

    __shared__ float warr[NCH];
    if (lane == 0) warr[w] = dv;
    __syncthreads();
    if (threadIdx.x == 0) {
        float s = 0.0f;
        #pragma unroll
        for (int i = 0; i < NCH; ++i) s += warr[i];
        out[0] = s / (float)(NCH * BINS);
    }
}

extern "C" void kernel_launch(void* const* d_in, const int* in_sizes, int n_in,
                              void* d_out, int out_size, void* d_ws, size_t ws_size,
                              hipStream_t stream) {
    const float* pred   = (const float*)d_in[0];
    const float* target = (const float*)d_in[1];
    float* part = (float*)d_ws;          // 1536*64 floats = 393 KB partials
    float* out  = (float*)d_out;

    hist_kernel<<<dim3(NBLK), dim3(THREADS), 0, stream>>>(
        pred, target, part);
    final_kernel<<<dim3(1), dim3(NCH * 64), 0, stream>>>(part, out);
}